// Round 13
// baseline (297.809 us; speedup 1.0000x reference)
//
#include <hip/hip_runtime.h>
#include <hip/hip_bf16.h>
#include <math.h>

#define NH   8
#define NSEQ 4096
#define NB   2
#define HID  256
#define VD   32
#define RANK 409      // 0-indexed; pos = 0.1*(4096-1) = 409.5 -> lerp(s[409],s[410],0.5)
#define NBIN 128      // candidate-space histogram bins (per wave)
#define CAND 704      // per-row candidate cap (mean 480, sd 20.6); multiple of 16
#define TG   0.1171875f  // raw-space threshold guess (scale>0 -> raw order == scaled order)

typedef float floatx4 __attribute__((ext_vector_type(4)));

__device__ __forceinline__ unsigned mbcnt64(unsigned long long m) {
  return __builtin_amdgcn_mbcnt_hi((unsigned)(m >> 32),
                                   __builtin_amdgcn_mbcnt_lo((unsigned)m, 0u));
}
__device__ __forceinline__ float wred_min(float x) {
#pragma unroll
  for (int d = 32; d; d >>= 1) x = fminf(x, __shfl_xor(x, d, 64));
  return x;
}
__device__ __forceinline__ float wred_max(float x) {
#pragma unroll
  for (int d = 32; d; d >>= 1) x = fmaxf(x, __shfl_xor(x, d, 64));
  return x;
}
__device__ __forceinline__ float wred_sum(float x) {
#pragma unroll
  for (int d = 32; d; d >>= 1) x += __shfl_xor(x, d, 64);
  return x;
}
__device__ __forceinline__ float gelu_tanh(float x) {
  float x3 = x * x * x;
  float inner = 0.7978845608028654f * (x + 0.044715f * x3);
  return 0.5f * x * (1.0f + tanhf(inner));
}

// ---------------- kernel A: value[h][n][b*32+k] = x @ weight; + scales ------

__global__ __launch_bounds__(256) void value_kernel(
    const float* __restrict__ x, const float* __restrict__ w,
    const float* __restrict__ r, float* __restrict__ value,
    float* __restrict__ scales) {
  const int tid = threadIdx.x;

  if (blockIdx.x == 0 && tid < NH) {
    double rv = (double)r[tid];
    const float c0 = (float)(0.25 * 3.141592653589793 * (1.0 - 1e-07));
    float s1 = (float)sin(rv);
    float t = c0 * (1.0f + s1);
    scales[tid] = (float)tan((double)t);
  }

  const int n0 = blockIdx.x * 8;
  __shared__ float sx[NB][8][HID];
#pragma unroll
  for (int i = 0; i < 16; i++) {
    int idx = i * 256 + tid;
    int b = idx >> 11;
    int rem = idx & 2047;
    int nn = rem >> 8;
    int j = rem & 255;
    sx[b][nn][j] = x[((size_t)b * NSEQ + n0 + nn) * HID + j];
  }
  __syncthreads();

  const int h = tid >> 5, k = tid & 31;
  float acc[NB][8];
#pragma unroll
  for (int b = 0; b < NB; b++)
#pragma unroll
    for (int nn = 0; nn < 8; nn++) acc[b][nn] = 0.f;

  const float* wp = w + (size_t)h * HID * VD + k;
  for (int j4 = 0; j4 < HID; j4 += 4) {
    float wv0 = wp[(size_t)(j4 + 0) * VD];
    float wv1 = wp[(size_t)(j4 + 1) * VD];
    float wv2 = wp[(size_t)(j4 + 2) * VD];
    float wv3 = wp[(size_t)(j4 + 3) * VD];
#pragma unroll
    for (int b = 0; b < NB; b++) {
#pragma unroll
      for (int nn = 0; nn < 8; nn++) {
        const float4 xv = *reinterpret_cast<const float4*>(&sx[b][nn][j4]);
        float a = acc[b][nn];
        a = fmaf(xv.x, wv0, a);
        a = fmaf(xv.y, wv1, a);
        a = fmaf(xv.z, wv2, a);
        a = fmaf(xv.w, wv3, a);
        acc[b][nn] = a;
      }
    }
  }
#pragma unroll
  for (int b = 0; b < NB; b++)
#pragma unroll
    for (int nn = 0; nn < 8; nn++)
      value[((size_t)h * NSEQ + n0 + nn) * (NB * VD) + b * VD + k] = acc[b][nn];
}

// ---------------- kernel B1: selection -> (weight, byteoff) lists ----------
// wave per row, zero barriers. Writes padded list (mult of 16) + (invd, Mpad).

#define PROCR(CV, G, T)                                                                   \
  do {                                                                                    \
    const int nb_ = ((G) << 16) | (lane << 10);                                           \
    { bool s = (CV).x <= (T); unsigned long long m = __ballot(s);                         \
      unsigned p = nc + mbcnt64(m);                                                       \
      if (s && p < CAND) sc[p] = make_float2((CV).x * scale, __int_as_float(nb_));        \
      nc += (unsigned)__popcll(m); }                                                      \
    { bool s = (CV).y <= (T); unsigned long long m = __ballot(s);                         \
      unsigned p = nc + mbcnt64(m);                                                       \
      if (s && p < CAND) sc[p] = make_float2((CV).y * scale, __int_as_float(nb_ | 256));  \
      nc += (unsigned)__popcll(m); }                                                      \
    { bool s = (CV).z <= (T); unsigned long long m = __ballot(s);                         \
      unsigned p = nc + mbcnt64(m);                                                       \
      if (s && p < CAND) sc[p] = make_float2((CV).z * scale, __int_as_float(nb_ | 512));  \
      nc += (unsigned)__popcll(m); }                                                      \
    { bool s = (CV).w <= (T); unsigned long long m = __ballot(s);                         \
      unsigned p = nc + mbcnt64(m);                                                       \
      if (s && p < CAND) sc[p] = make_float2((CV).w * scale, __int_as_float(nb_ | 768));  \
      nc += (unsigned)__popcll(m); }                                                      \
  } while (0)

#define PROCS(CV, G, TS)                                                                  \
  do {                                                                                    \
    const int nb_ = ((G) << 16) | (lane << 10);                                           \
    { float t_ = (CV).x * scale; bool s = t_ <= (TS); unsigned long long m = __ballot(s); \
      unsigned p = nc + mbcnt64(m);                                                       \
      if (s && p < CAND) sc[p] = make_float2(t_, __int_as_float(nb_));                    \
      nc += (unsigned)__popcll(m); }                                                      \
    { float t_ = (CV).y * scale; bool s = t_ <= (TS); unsigned long long m = __ballot(s); \
      unsigned p = nc + mbcnt64(m);                                                       \
      if (s && p < CAND) sc[p] = make_float2(t_, __int_as_float(nb_ | 256));              \
      nc += (unsigned)__popcll(m); }                                                      \
    { float t_ = (CV).z * scale; bool s = t_ <= (TS); unsigned long long m = __ballot(s); \
      unsigned p = nc + mbcnt64(m);                                                       \
      if (s && p < CAND) sc[p] = make_float2(t_, __int_as_float(nb_ | 512));              \
      nc += (unsigned)__popcll(m); }                                                      \
    { float t_ = (CV).w * scale; bool s = t_ <= (TS); unsigned long long m = __ballot(s); \
      unsigned p = nc + mbcnt64(m);                                                       \
      if (s && p < CAND) sc[p] = make_float2(t_, __int_as_float(nb_ | 768));              \
      nc += (unsigned)__popcll(m); }                                                      \
  } while (0)

#define CNT1(U)                                                        \
  do {                                                                 \
    bool s_ = (U) <= Tc;                                               \
    cN += (unsigned)__popcll(__ballot(s_));                            \
    if (s_) vb = fmaxf(vb, (U)); else vs = fminf(vs, (U));             \
  } while (0)

__global__ __launch_bounds__(256, 5) void select_kernel(
    const float* __restrict__ m_dist, const float* __restrict__ scales,
    float2* __restrict__ lists, float2* __restrict__ meta) {
  const int tid = threadIdx.x;
  const int lane = tid & 63;
  const int wv = tid >> 6;
  const int bid = blockIdx.x;
  const int h = bid & 7;
  const int q = (bid >> 3) * 4 + wv;
  const unsigned rrow = (unsigned)(h * NSEQ + q);

  __shared__ float2 s_cand[4][CAND];   // 22528 B per-wave segments
  __shared__ unsigned s_hist[4][NBIN]; // 2048 B
  __shared__ float s_small[4][48];     // 768 B
  __shared__ unsigned s_cnt[4];

  float2* sc = s_cand[wv];
  unsigned* sh = s_hist[wv];
  float* ssm = s_small[wv];
  unsigned* scn = &s_cnt[wv];

  const float scale = scales[h];
  const floatx4* row4 =
      reinterpret_cast<const floatx4*>(m_dist + (size_t)rrow * NSEQ) + lane;

  // ---- hot stream: 4-deep pipelined, threshold TG ----
  unsigned nc = 0;
  {
    floatx4 c0 = __builtin_nontemporal_load(row4 + 0 * 64);
    floatx4 c1 = __builtin_nontemporal_load(row4 + 1 * 64);
    floatx4 c2 = __builtin_nontemporal_load(row4 + 2 * 64);
    floatx4 c3 = __builtin_nontemporal_load(row4 + 3 * 64);
    floatx4 n0 = __builtin_nontemporal_load(row4 + 4 * 64);
    floatx4 n1 = __builtin_nontemporal_load(row4 + 5 * 64);
    floatx4 n2 = __builtin_nontemporal_load(row4 + 6 * 64);
    floatx4 n3 = __builtin_nontemporal_load(row4 + 7 * 64);
    PROCR(c0, 0, TG); PROCR(c1, 1, TG); PROCR(c2, 2, TG); PROCR(c3, 3, TG);
    c0 = n0; c1 = n1; c2 = n2; c3 = n3;
    n0 = __builtin_nontemporal_load(row4 + 8 * 64);
    n1 = __builtin_nontemporal_load(row4 + 9 * 64);
    n2 = __builtin_nontemporal_load(row4 + 10 * 64);
    n3 = __builtin_nontemporal_load(row4 + 11 * 64);
    PROCR(c0, 4, TG); PROCR(c1, 5, TG); PROCR(c2, 6, TG); PROCR(c3, 7, TG);
    c0 = n0; c1 = n1; c2 = n2; c3 = n3;
    n0 = __builtin_nontemporal_load(row4 + 12 * 64);
    n1 = __builtin_nontemporal_load(row4 + 13 * 64);
    n2 = __builtin_nontemporal_load(row4 + 14 * 64);
    n3 = __builtin_nontemporal_load(row4 + 15 * 64);
    PROCR(c0, 8, TG); PROCR(c1, 9, TG); PROCR(c2, 10, TG); PROCR(c3, 11, TG);
    c0 = n0; c1 = n1; c2 = n2; c3 = n3;
    PROCR(c0, 12, TG); PROCR(c1, 13, TG); PROCR(c2, 14, TG); PROCR(c3, 15, TG);
  }

  float TselS = TG * scale;
  bool exact = false;
  float ex409 = 0.f, ex410 = 0.f;

  if (nc < (unsigned)(RANK + 2) || nc > (unsigned)CAND) {
    // ---- cold (wave-local): count-only bisect; exact-tie path on collapse ----
    float lo, hi;
    if (nc < (unsigned)(RANK + 2)) { lo = TG; hi = 1.0f; }
    else { lo = 0.f; hi = TG; }
    float T = TG;
    bool collapse = false, ok = false;
    for (int it = 0; it < 40; ++it) {
      float mid = 0.5f * (lo + hi);
      if (!(mid > lo && mid < hi)) { collapse = true; break; }
      unsigned cN = 0;
      float vb = -INFINITY, vs = INFINITY;
      const float Tc = mid;
#pragma unroll 2
      for (int ch = 0; ch < 16; ++ch) {
        floatx4 cv = __builtin_nontemporal_load(row4 + ch * 64);
        CNT1(cv.x); CNT1(cv.y); CNT1(cv.z); CNT1(cv.w);
      }
      if (cN >= (unsigned)(RANK + 2) && cN <= (unsigned)CAND) { T = mid; ok = true; break; }
      if (cN < (unsigned)(RANK + 2)) lo = mid; else hi = mid;
    }
    if (collapse) {
      unsigned cN = 0;
      float vb = -INFINITY, vs = INFINITY;
      {
        const float Tc = lo;
#pragma unroll 2
        for (int ch = 0; ch < 16; ++ch) {
          floatx4 cv = __builtin_nontemporal_load(row4 + ch * 64);
          CNT1(cv.x); CNT1(cv.y); CNT1(cv.z); CNT1(cv.w);
        }
      }
      vb = wred_max(vb);
      vs = wred_min(vs);
      float s409r, s410r;
      if (cN >= (unsigned)(RANK + 2)) { s409r = vb; s410r = vb; }
      else if (cN == (unsigned)(RANK + 1)) { s409r = vb; s410r = vs; }
      else { s409r = vs; s410r = vs; }
      ex409 = s409r * scale;
      ex410 = s410r * scale;
      exact = true;
      float thrS = 0.5f * ex409 + 0.5f * ex410;
      TselS = fmaxf(thrS, 1e-30f);
      nc = 0;
#pragma unroll 2
      for (int ch = 0; ch < 16; ++ch) {
        floatx4 cv = __builtin_nontemporal_load(row4 + ch * 64);
        PROCS(cv, ch, thrS);
      }
    } else if (ok) {
      TselS = T * scale;
      nc = 0;
      const float Tf = T;
#pragma unroll 2
      for (int ch = 0; ch < 16; ++ch) {
        floatx4 cv = __builtin_nontemporal_load(row4 + ch * 64);
        PROCR(cv, ch, Tf);
      }
    }
  }
  if (nc > (unsigned)CAND) nc = (unsigned)CAND;  // unreachable safety

  // ---- histogram + fused min over candidates ----
  sh[lane] = 0u;
  sh[lane + 64] = 0u;
  const float binscale = (float)NBIN / TselS;
  float mn = INFINITY;
  for (unsigned e = lane; e < nc; e += 64) {
    float vv = sc[e].x;
    mn = fminf(mn, vv);
    int b = (int)(vv * binscale);
    b = b < 0 ? 0 : (b > NBIN - 1 ? NBIN - 1 : b);
    atomicAdd(&sh[b], 1u);
  }
  const float minT = wred_min(mn);

  float v409, v410;
  if (exact) {
    v409 = ex409;
    v410 = ex410;
  } else {
    // locate rank bin: 2 bins/lane, wave exclusive scan
    unsigned c2 = sh[2 * lane] + sh[2 * lane + 1];
    unsigned incl = c2;
#pragma unroll
    for (int d = 1; d < 64; d <<= 1) {
      unsigned o = __shfl_up(incl, d, 64);
      if (lane >= d) incl += o;
    }
    unsigned b2 = incl - c2;
    unsigned tb_l = 0, bt_l = 0;
    bool win = (b2 <= (unsigned)RANK && (unsigned)RANK < b2 + c2);
    if (win) {
      unsigned h0 = sh[2 * lane];
      if ((unsigned)RANK < b2 + h0) { tb_l = 2u * lane; bt_l = b2; }
      else { tb_l = 2u * lane + 1u; bt_l = b2 + h0; }
    }
    unsigned long long wm = __ballot(win);
    int wl = (int)__ffsll(wm) - 1;
    if (wl < 0) wl = 0;
    unsigned tb = (unsigned)__shfl((int)tb_l, wl, 64);
    unsigned base_tb = (unsigned)__shfl((int)bt_l, wl, 64);

    // in-bin collect + min-above-bin
    *scn = 0u;
    float mgt = INFINITY;
    for (unsigned e = lane; e < nc; e += 64) {
      float v = sc[e].x;
      int b = (int)(v * binscale);
      b = b < 0 ? 0 : (b > NBIN - 1 ? NBIN - 1 : b);
      if ((unsigned)b == tb) {
        unsigned p = atomicAdd(scn, 1u);
        if (p < 48u) ssm[p] = v;
      } else if ((unsigned)b > tb) {
        mgt = fminf(mgt, v);
      }
    }
    mgt = wred_min(mgt);
    unsigned cbin = *scn;

    if (cbin <= 48u) {
      float cand = (lane < (int)cbin) ? ssm[lane] : INFINITY;
      unsigned less = 0, eq = 0;
      for (unsigned k = 0; k < cbin; k++) {
        float g = ssm[k];
        less += (g < cand) ? 1u : 0u;
        eq += (g == cand) ? 1u : 0u;
      }
      unsigned gl = base_tb + less;
      bool w9 = (lane < (int)cbin) && gl <= (unsigned)RANK && (unsigned)RANK < gl + eq;
      bool w10 = (lane < (int)cbin) && gl <= (unsigned)(RANK + 1) && (unsigned)(RANK + 1) < gl + eq;
      v409 = wred_min(w9 ? cand : INFINITY);
      float t10 = wred_min(w10 ? cand : INFINITY);
      v410 = isinf(t10) ? mgt : t10;
    } else {
      // pathological clustering fallback: O(nc^2/64) exact
      float a9 = INFINITY, a10 = INFINITY;
      for (unsigned e = lane; e < nc; e += 64) {
        float v = sc[e].x;
        int b = (int)(v * binscale);
        b = b < 0 ? 0 : (b > NBIN - 1 ? NBIN - 1 : b);
        if ((unsigned)b == tb) {
          unsigned less = 0, eq = 0;
          for (unsigned k = 0; k < nc; k++) {
            float g = sc[k].x;
            less += (g < v) ? 1u : 0u;
            eq += (g == v) ? 1u : 0u;
          }
          if (less <= (unsigned)RANK && (unsigned)RANK < less + eq) a9 = v;
          if (less <= (unsigned)(RANK + 1) && (unsigned)(RANK + 1) < less + eq) a10 = v;
        }
      }
      v409 = wred_min(a9);
      float t10 = wred_min(a10);
      v410 = isinf(t10) ? mgt : t10;
    }
    if (isinf(v409)) v409 = mgt;  // unreachable guard
  }
  const float thr = 0.5f * v409 + 0.5f * v410;  // jax lerp midpoint, frac=0.5

  // ---- weight pass (fixed order -> deterministic psum), pad, write list ----
  float psum = 0.f;
  for (unsigned e = lane; e < nc; e += 64) {
    float2 t = sc[e];
    float w = (t.x <= thr) ? __expf(minT - t.x) : 0.f;
    psum += w;
    sc[e] = make_float2(w, t.y);
  }
  float denom = wred_sum(psum);
  float invd = denom > 0.f ? 1.0f / denom : 0.f;
  const unsigned padded = (nc + 15u) & ~15u;
  if ((unsigned)lane < padded - nc) sc[nc + lane] = make_float2(0.f, __int_as_float(0));

  const float4* sc4 = reinterpret_cast<const float4*>(sc);
  float4* gl4 = reinterpret_cast<float4*>(lists + (size_t)rrow * CAND);
  for (unsigned e = lane; e < padded / 2; e += 64) gl4[e] = sc4[e];
  if (lane == 0) meta[rrow] = make_float2(invd, __int_as_float((int)padded));
}

// ---------------- kernel B2: gather lists x value -> gelu -> out ------------

__global__ __launch_bounds__(256, 6) void gather_kernel(
    const float* __restrict__ value, const float2* __restrict__ lists,
    const float2* __restrict__ meta, float* __restrict__ out) {
  const int tid = threadIdx.x;
  const int lane = tid & 63;
  const int wv = tid >> 6;
  const int bid = blockIdx.x;
  const int h = bid & 7;  // head == presumed XCD (value slice L2-resident)
  const int q = (bid >> 3) * 4 + wv;
  const unsigned rrow = (unsigned)(h * NSEQ + q);

  __shared__ float4 s_l4[4][CAND / 2];  // 22528 B per-wave list staging
  float4* sl4 = s_l4[wv];

  float2 m2 = meta[rrow];
  const float invd = m2.x;
  const unsigned padded = (unsigned)__float_as_int(m2.y);

  const float4* gl4 = reinterpret_cast<const float4*>(lists + (size_t)rrow * CAND);
  for (unsigned e = lane; e < padded / 2; e += 64) sl4[e] = gl4[e];
  const float2* seg = reinterpret_cast<const float2*>(sl4);

  // gather: 16 lanes x float4 per entry row, 4 entries per iter (wave-local LDS)
  const char* vpb = (const char*)(value + (size_t)h * (NSEQ * NB * VD)) + (lane & 15) * 16;
  floatx4 acc4 = {0.f, 0.f, 0.f, 0.f};
  for (unsigned t0 = 0; t0 < padded; t0 += 16) {
    unsigned j = t0 + (unsigned)(lane >> 4);
    float2 c0 = seg[j];
    float2 c1 = seg[j + 4];
    float2 c2e = seg[j + 8];
    float2 c3 = seg[j + 12];
    floatx4 a0 = *reinterpret_cast<const floatx4*>(vpb + __float_as_int(c0.y));
    floatx4 a1 = *reinterpret_cast<const floatx4*>(vpb + __float_as_int(c1.y));
    floatx4 a2 = *reinterpret_cast<const floatx4*>(vpb + __float_as_int(c2e.y));
    floatx4 a3 = *reinterpret_cast<const floatx4*>(vpb + __float_as_int(c3.y));
    acc4.x = fmaf(c0.x, a0.x, acc4.x);
    acc4.y = fmaf(c0.x, a0.y, acc4.y);
    acc4.z = fmaf(c0.x, a0.z, acc4.z);
    acc4.w = fmaf(c0.x, a0.w, acc4.w);
    acc4.x = fmaf(c1.x, a1.x, acc4.x);
    acc4.y = fmaf(c1.x, a1.y, acc4.y);
    acc4.z = fmaf(c1.x, a1.z, acc4.z);
    acc4.w = fmaf(c1.x, a1.w, acc4.w);
    acc4.x = fmaf(c2e.x, a2.x, acc4.x);
    acc4.y = fmaf(c2e.x, a2.y, acc4.y);
    acc4.z = fmaf(c2e.x, a2.z, acc4.z);
    acc4.w = fmaf(c2e.x, a2.w, acc4.w);
    acc4.x = fmaf(c3.x, a3.x, acc4.x);
    acc4.y = fmaf(c3.x, a3.y, acc4.y);
    acc4.z = fmaf(c3.x, a3.z, acc4.z);
    acc4.w = fmaf(c3.x, a3.w, acc4.w);
  }
  // sum the 4 sixteen-lane groups
#pragma unroll
  for (int d = 16; d < 64; d <<= 1) {
    acc4.x += __shfl_xor(acc4.x, d, 64);
    acc4.y += __shfl_xor(acc4.y, d, 64);
    acc4.z += __shfl_xor(acc4.z, d, 64);
    acc4.w += __shfl_xor(acc4.w, d, 64);
  }

  if (lane < 16) {
    float o0 = gelu_tanh(acc4.x * invd);
    float o1 = gelu_tanh(acc4.y * invd);
    float o2 = gelu_tanh(acc4.z * invd);
    float o3 = gelu_tanh(acc4.w * invd);
    int col = lane * 4;
    int bb = col >> 5, kk = col & 31;
    float4 o4 = make_float4(o0, o1, o2, o3);
    *reinterpret_cast<float4*>(&out[((size_t)bb * NSEQ + q) * (NH * VD) + (size_t)h * VD + kk]) = o4;
  }
}

// ---------------- launch ----------------------------------------------------

extern "C" void kernel_launch(void* const* d_in, const int* in_sizes, int n_in,
                              void* d_out, int out_size, void* d_ws, size_t ws_size,
                              hipStream_t stream) {
  const float* m_dist = (const float*)d_in[0];
  const float* x = (const float*)d_in[1];
  const float* r = (const float*)d_in[2];
  const float* w = (const float*)d_in[3];
  float* out = (float*)d_out;

  char* base = (char*)d_ws;
  float* value = (float*)base;                                   // 8 MB
  float* scales = value + (size_t)NH * NSEQ * NB * VD;           // + 8 floats
  float2* lists = (float2*)(base + (16u << 20));                 // 16 MB offset; 32768*704*8B = 184.5 MB
  float2* meta = (float2*)(base + (16u << 20) + (size_t)NH * NSEQ * CAND * 8);  // + 256 KB

  value_kernel<<<dim3(NSEQ / 8), dim3(256), 0, stream>>>(x, w, r, value, scales);
  select_kernel<<<dim3(NH * NSEQ / 4), dim3(256), 0, stream>>>(m_dist, scales, lists, meta);
  gather_kernel<<<dim3(NH * NSEQ / 4), dim3(256), 0, stream>>>(value, lists, meta, out);
}

// Round 14
// 264.558 us; speedup vs baseline: 1.1257x; 1.1257x over previous
//
#include <hip/hip_runtime.h>
#include <hip/hip_bf16.h>
#include <math.h>

#define NH   8
#define NSEQ 4096
#define NB   2
#define HID  256
#define VD   32
#define RANK 409      // 0-indexed; pos = 0.1*(4096-1) = 409.5 -> lerp(s[409],s[410],0.5)
#define NBIN 128      // candidate-space histogram bins (per wave)
#define CAND 704      // per-wave candidate cap (mean 480, sd 20.6); multiple of 16
#define TG   0.1171875f  // raw-space threshold guess (scale>0 -> raw order == scaled order)

typedef float floatx4 __attribute__((ext_vector_type(4)));

__device__ __forceinline__ unsigned mbcnt64(unsigned long long m) {
  return __builtin_amdgcn_mbcnt_hi((unsigned)(m >> 32),
                                   __builtin_amdgcn_mbcnt_lo((unsigned)m, 0u));
}
__device__ __forceinline__ float wred_min(float x) {
#pragma unroll
  for (int d = 32; d; d >>= 1) x = fminf(x, __shfl_xor(x, d, 64));
  return x;
}
__device__ __forceinline__ float wred_max(float x) {
#pragma unroll
  for (int d = 32; d; d >>= 1) x = fmaxf(x, __shfl_xor(x, d, 64));
  return x;
}
__device__ __forceinline__ float wred_sum(float x) {
#pragma unroll
  for (int d = 32; d; d >>= 1) x += __shfl_xor(x, d, 64);
  return x;
}
__device__ __forceinline__ float gelu_tanh(float x) {
  float x3 = x * x * x;
  float inner = 0.7978845608028654f * (x + 0.044715f * x3);
  return 0.5f * x * (1.0f + tanhf(inner));
}

// ---------------- kernel A: value[h][n][b*32+k] = x @ weight; + scales ------

__global__ __launch_bounds__(256) void value_kernel(
    const float* __restrict__ x, const float* __restrict__ w,
    const float* __restrict__ r, float* __restrict__ value,
    float* __restrict__ scales) {
  const int tid = threadIdx.x;

  if (blockIdx.x == 0 && tid < NH) {
    double rv = (double)r[tid];
    const float c0 = (float)(0.25 * 3.141592653589793 * (1.0 - 1e-07));
    float s1 = (float)sin(rv);
    float t = c0 * (1.0f + s1);
    scales[tid] = (float)tan((double)t);
  }

  const int n0 = blockIdx.x * 8;
  __shared__ float sx[NB][8][HID];
#pragma unroll
  for (int i = 0; i < 16; i++) {
    int idx = i * 256 + tid;
    int b = idx >> 11;
    int rem = idx & 2047;
    int nn = rem >> 8;
    int j = rem & 255;
    sx[b][nn][j] = x[((size_t)b * NSEQ + n0 + nn) * HID + j];
  }
  __syncthreads();

  const int h = tid >> 5, k = tid & 31;
  float acc[NB][8];
#pragma unroll
  for (int b = 0; b < NB; b++)
#pragma unroll
    for (int nn = 0; nn < 8; nn++) acc[b][nn] = 0.f;

  const float* wp = w + (size_t)h * HID * VD + k;
  for (int j4 = 0; j4 < HID; j4 += 4) {
    float wv0 = wp[(size_t)(j4 + 0) * VD];
    float wv1 = wp[(size_t)(j4 + 1) * VD];
    float wv2 = wp[(size_t)(j4 + 2) * VD];
    float wv3 = wp[(size_t)(j4 + 3) * VD];
#pragma unroll
    for (int b = 0; b < NB; b++) {
#pragma unroll
      for (int nn = 0; nn < 8; nn++) {
        const float4 xv = *reinterpret_cast<const float4*>(&sx[b][nn][j4]);
        float a = acc[b][nn];
        a = fmaf(xv.x, wv0, a);
        a = fmaf(xv.y, wv1, a);
        a = fmaf(xv.z, wv2, a);
        a = fmaf(xv.w, wv3, a);
        acc[b][nn] = a;
      }
    }
  }
#pragma unroll
  for (int b = 0; b < NB; b++)
#pragma unroll
    for (int nn = 0; nn < 8; nn++)
      value[((size_t)h * NSEQ + n0 + nn) * (NB * VD) + b * VD + k] = acc[b][nn];
}

// ---------------- kernel B: ONE WAVE PER ROW, zero __syncthreads ------------
// Selection done in RAW space (monotone fl(u*scale) => sorted_scaled[k] ==
// fl(sorted_raw[k]*scale)); scale applied only to v409/v410/min + weight pass.

// raw-space test + RAW store
#define PROCR(CV, G, T)                                                            \
  do {                                                                             \
    const int nb_ = ((G) << 16) | (lane << 10);                                    \
    { bool s = (CV).x <= (T); unsigned long long m = __ballot(s);                  \
      unsigned p = nc + mbcnt64(m);                                                \
      if (s && p < CAND) sc[p] = make_float2((CV).x, __int_as_float(nb_));         \
      nc += (unsigned)__popcll(m); }                                               \
    { bool s = (CV).y <= (T); unsigned long long m = __ballot(s);                  \
      unsigned p = nc + mbcnt64(m);                                                \
      if (s && p < CAND) sc[p] = make_float2((CV).y, __int_as_float(nb_ | 256));   \
      nc += (unsigned)__popcll(m); }                                               \
    { bool s = (CV).z <= (T); unsigned long long m = __ballot(s);                  \
      unsigned p = nc + mbcnt64(m);                                                \
      if (s && p < CAND) sc[p] = make_float2((CV).z, __int_as_float(nb_ | 512));   \
      nc += (unsigned)__popcll(m); }                                               \
    { bool s = (CV).w <= (T); unsigned long long m = __ballot(s);                  \
      unsigned p = nc + mbcnt64(m);                                                \
      if (s && p < CAND) sc[p] = make_float2((CV).w, __int_as_float(nb_ | 768));   \
      nc += (unsigned)__popcll(m); }                                               \
  } while (0)

// scaled-space test + SCALED store (collapse path only)
#define PROCS(CV, G, TS)                                                                  \
  do {                                                                                    \
    const int nb_ = ((G) << 16) | (lane << 10);                                           \
    { float t_ = (CV).x * scale; bool s = t_ <= (TS); unsigned long long m = __ballot(s); \
      unsigned p = nc + mbcnt64(m);                                                       \
      if (s && p < CAND) sc[p] = make_float2(t_, __int_as_float(nb_));                    \
      nc += (unsigned)__popcll(m); }                                                      \
    { float t_ = (CV).y * scale; bool s = t_ <= (TS); unsigned long long m = __ballot(s); \
      unsigned p = nc + mbcnt64(m);                                                       \
      if (s && p < CAND) sc[p] = make_float2(t_, __int_as_float(nb_ | 256));              \
      nc += (unsigned)__popcll(m); }                                                      \
    { float t_ = (CV).z * scale; bool s = t_ <= (TS); unsigned long long m = __ballot(s); \
      unsigned p = nc + mbcnt64(m);                                                       \
      if (s && p < CAND) sc[p] = make_float2(t_, __int_as_float(nb_ | 512));              \
      nc += (unsigned)__popcll(m); }                                                      \
    { float t_ = (CV).w * scale; bool s = t_ <= (TS); unsigned long long m = __ballot(s); \
      unsigned p = nc + mbcnt64(m);                                                       \
      if (s && p < CAND) sc[p] = make_float2(t_, __int_as_float(nb_ | 768));              \
      nc += (unsigned)__popcll(m); }                                                      \
  } while (0)

#define CNT1(U)                                                        \
  do {                                                                 \
    bool s_ = (U) <= Tc;                                               \
    cN += (unsigned)__popcll(__ballot(s_));                            \
    if (s_) vb = fmaxf(vb, (U)); else vs = fminf(vs, (U));             \
  } while (0)

__global__ __launch_bounds__(256, 6) void attn_kernel(
    const float* __restrict__ m_dist, const float* __restrict__ value,
    const float* __restrict__ scales, float* __restrict__ out) {
  const int tid = threadIdx.x;
  const int lane = tid & 63;
  const int wv = tid >> 6;
  // 8192 blocks of 4 independent waves; bid&7 -> head == XCD (value L2-resident)
  const int bid = blockIdx.x;
  const int h = bid & 7;
  const int q = (bid >> 3) * 4 + wv;

  __shared__ float2 s_cand[4][CAND];   // 22528 B: per-wave (raw, byteoff)->(w, byteoff)
  __shared__ unsigned s_hist[4][NBIN]; // 2048 B
  __shared__ float s_small[4][48];     // 768 B
  __shared__ unsigned s_cnt[4];        // 16 B   (total 25360 B -> 6 blocks/CU)

  float2* sc = s_cand[wv];
  unsigned* sh = s_hist[wv];
  float* ssm = s_small[wv];
  unsigned* scn = &s_cnt[wv];

  const float scale = scales[h];
  const floatx4* row4 =
      reinterpret_cast<const floatx4*>(m_dist + ((size_t)(h * NSEQ + q)) * NSEQ) + lane;

  // ---- HOT stream: 4 loads in flight, threshold TG, RAW store ----
  unsigned nc = 0;
  {
    floatx4 c0 = __builtin_nontemporal_load(row4 + 0 * 64);
    floatx4 c1 = __builtin_nontemporal_load(row4 + 1 * 64);
    floatx4 n0 = __builtin_nontemporal_load(row4 + 2 * 64);
    floatx4 n1 = __builtin_nontemporal_load(row4 + 3 * 64);
    PROCR(c0, 0, TG); PROCR(c1, 1, TG);
    c0 = n0; c1 = n1;
    n0 = __builtin_nontemporal_load(row4 + 4 * 64);
    n1 = __builtin_nontemporal_load(row4 + 5 * 64);
    PROCR(c0, 2, TG); PROCR(c1, 3, TG);
    c0 = n0; c1 = n1;
    n0 = __builtin_nontemporal_load(row4 + 6 * 64);
    n1 = __builtin_nontemporal_load(row4 + 7 * 64);
    PROCR(c0, 4, TG); PROCR(c1, 5, TG);
    c0 = n0; c1 = n1;
    n0 = __builtin_nontemporal_load(row4 + 8 * 64);
    n1 = __builtin_nontemporal_load(row4 + 9 * 64);
    PROCR(c0, 6, TG); PROCR(c1, 7, TG);
    c0 = n0; c1 = n1;
    n0 = __builtin_nontemporal_load(row4 + 10 * 64);
    n1 = __builtin_nontemporal_load(row4 + 11 * 64);
    PROCR(c0, 8, TG); PROCR(c1, 9, TG);
    c0 = n0; c1 = n1;
    n0 = __builtin_nontemporal_load(row4 + 12 * 64);
    n1 = __builtin_nontemporal_load(row4 + 13 * 64);
    PROCR(c0, 10, TG); PROCR(c1, 11, TG);
    c0 = n0; c1 = n1;
    n0 = __builtin_nontemporal_load(row4 + 14 * 64);
    n1 = __builtin_nontemporal_load(row4 + 15 * 64);
    PROCR(c0, 12, TG); PROCR(c1, 13, TG);
    c0 = n0; c1 = n1;
    PROCR(c0, 14, TG); PROCR(c1, 15, TG);
  }

  float Tsel = TG;    // raw-space candidate range
  bool exact = false; // collapse path: sc holds SCALED values, ranks known
  float ex409 = 0.f, ex410 = 0.f;

  if (nc < (unsigned)(RANK + 2) || nc > (unsigned)CAND) {
    // ---- cold (wave-local, ~never on this data): count-only bisect ----
    float lo, hi;
    if (nc < (unsigned)(RANK + 2)) { lo = TG; hi = 1.0f; }
    else { lo = 0.f; hi = TG; }
    bool collapse = false, ok = false;
    for (int it = 0; it < 40; ++it) {
      float mid = 0.5f * (lo + hi);
      if (!(mid > lo && mid < hi)) { collapse = true; break; }
      unsigned cN = 0;
      float vb = -INFINITY, vs = INFINITY;
      const float Tc = mid;
#pragma unroll 2
      for (int ch = 0; ch < 16; ++ch) {
        floatx4 cv = __builtin_nontemporal_load(row4 + ch * 64);
        CNT1(cv.x); CNT1(cv.y); CNT1(cv.z); CNT1(cv.w);
      }
      if (cN >= (unsigned)(RANK + 2) && cN <= (unsigned)CAND) { Tsel = mid; ok = true; break; }
      if (cN < (unsigned)(RANK + 2)) lo = mid; else hi = mid;
    }
    if (collapse) {
      // exact tie handling at lo (raw): derive both order stats directly
      unsigned cN = 0;
      float vb = -INFINITY, vs = INFINITY;
      {
        const float Tc = lo;
#pragma unroll 2
        for (int ch = 0; ch < 16; ++ch) {
          floatx4 cv = __builtin_nontemporal_load(row4 + ch * 64);
          CNT1(cv.x); CNT1(cv.y); CNT1(cv.z); CNT1(cv.w);
        }
      }
      vb = wred_max(vb);
      vs = wred_min(vs);
      float s409r, s410r;
      if (cN >= (unsigned)(RANK + 2)) { s409r = vb; s410r = vb; }
      else if (cN == (unsigned)(RANK + 1)) { s409r = vb; s410r = vs; }
      else { s409r = vs; s410r = vs; }
      ex409 = s409r * scale;
      ex410 = s410r * scale;
      exact = true;
      float thrS = 0.5f * ex409 + 0.5f * ex410;
      nc = 0;
#pragma unroll 2
      for (int ch = 0; ch < 16; ++ch) {
        floatx4 cv = __builtin_nontemporal_load(row4 + ch * 64);
        PROCS(cv, ch, thrS);
      }
    } else if (ok) {
      nc = 0;
      const float Tf = Tsel;
#pragma unroll 2
      for (int ch = 0; ch < 16; ++ch) {
        floatx4 cv = __builtin_nontemporal_load(row4 + ch * 64);
        PROCR(cv, ch, Tf);
      }
    }
  }
  if (nc > (unsigned)CAND) nc = (unsigned)CAND;  // unreachable safety
  const float smul = exact ? 1.0f : scale;  // sc values raw (normal) / scaled (exact)

  // ---- per-wave 128-bin histogram over candidates + fused min (sc space) ----
  sh[lane] = 0u;
  sh[lane + 64] = 0u;
  const float binscale = exact ? 0.f : (float)NBIN / Tsel;
  float mn = INFINITY;
  for (unsigned e = lane; e < nc; e += 64) {
    float vv = sc[e].x;
    mn = fminf(mn, vv);
    int b = (int)(vv * binscale);
    b = b < 0 ? 0 : (b > NBIN - 1 ? NBIN - 1 : b);
    atomicAdd(&sh[b], 1u);
  }
  const float minT = wred_min(mn) * smul;  // scaled global min (monotone fl)

  float v409, v410;  // SCALED order statistics
  if (exact) {
    v409 = ex409;
    v410 = ex410;
  } else {
    // ---- locate rank bin: 2 bins/lane, wave exclusive scan ----
    unsigned c2 = sh[2 * lane] + sh[2 * lane + 1];
    unsigned incl = c2;
#pragma unroll
    for (int d = 1; d < 64; d <<= 1) {
      unsigned o = __shfl_up(incl, d, 64);
      if (lane >= d) incl += o;
    }
    unsigned b2 = incl - c2;
    unsigned tb_l = 0, bt_l = 0;
    bool win = (b2 <= (unsigned)RANK && (unsigned)RANK < b2 + c2);
    if (win) {
      unsigned h0 = sh[2 * lane];
      if ((unsigned)RANK < b2 + h0) { tb_l = 2u * lane; bt_l = b2; }
      else { tb_l = 2u * lane + 1u; bt_l = b2 + h0; }
    }
    unsigned long long wm = __ballot(win);
    int wl = (int)__ffsll(wm) - 1;
    if (wl < 0) wl = 0;  // unreachable guard
    unsigned tb = (unsigned)__shfl((int)tb_l, wl, 64);
    unsigned base_tb = (unsigned)__shfl((int)bt_l, wl, 64);

    // ---- in-bin collect + min-above-bin (raw) ----
    *scn = 0u;
    float mgt = INFINITY;
    for (unsigned e = lane; e < nc; e += 64) {
      float v = sc[e].x;
      int b = (int)(v * binscale);
      b = b < 0 ? 0 : (b > NBIN - 1 ? NBIN - 1 : b);
      if ((unsigned)b == tb) {
        unsigned p = atomicAdd(scn, 1u);
        if (p < 48u) ssm[p] = v;
      } else if ((unsigned)b > tb) {
        mgt = fminf(mgt, v);
      }
    }
    mgt = wred_min(mgt);
    unsigned cbin = *scn;

    // ---- exact raw ranks RANK / RANK+1 ----
    float r409, r410;
    if (cbin <= 48u) {
      float cand = (lane < (int)cbin) ? ssm[lane] : INFINITY;
      unsigned less = 0, eq = 0;
      for (unsigned k = 0; k < cbin; k++) {
        float g = ssm[k];
        less += (g < cand) ? 1u : 0u;
        eq += (g == cand) ? 1u : 0u;
      }
      unsigned gl = base_tb + less;
      bool w9 = (lane < (int)cbin) && gl <= (unsigned)RANK && (unsigned)RANK < gl + eq;
      bool w10 = (lane < (int)cbin) && gl <= (unsigned)(RANK + 1) && (unsigned)(RANK + 1) < gl + eq;
      r409 = wred_min(w9 ? cand : INFINITY);
      float t10 = wred_min(w10 ? cand : INFINITY);
      r410 = isinf(t10) ? mgt : t10;
    } else {
      // pathological clustering fallback: O(nc^2/64) exact (never taken here)
      float a9 = INFINITY, a10 = INFINITY;
      for (unsigned e = lane; e < nc; e += 64) {
        float v = sc[e].x;
        int b = (int)(v * binscale);
        b = b < 0 ? 0 : (b > NBIN - 1 ? NBIN - 1 : b);
        if ((unsigned)b == tb) {
          unsigned less = 0, eq = 0;
          for (unsigned k = 0; k < nc; k++) {
            float g = sc[k].x;
            less += (g < v) ? 1u : 0u;
            eq += (g == v) ? 1u : 0u;
          }
          if (less <= (unsigned)RANK && (unsigned)RANK < less + eq) a9 = v;
          if (less <= (unsigned)(RANK + 1) && (unsigned)(RANK + 1) < less + eq) a10 = v;
        }
      }
      r409 = wred_min(a9);
      float t10 = wred_min(a10);
      r410 = isinf(t10) ? mgt : t10;
    }
    if (isinf(r409)) r409 = mgt;  // unreachable guard
    v409 = r409 * scale;          // fl(sorted_raw[k]*scale) == sorted_scaled[k]
    v410 = r410 * scale;
  }
  const float thr = 0.5f * v409 + 0.5f * v410;  // jax lerp midpoint, frac=0.5

  // ---- weight pass (fixed strided order -> deterministic psum) ----
  float psum = 0.f;
  for (unsigned e = lane; e < nc; e += 64) {
    float2 t = sc[e];
    float ts = t.x * smul;  // scaled value
    float w = (ts <= thr) ? __expf(minT - ts) : 0.f;
    psum += w;
    sc[e] = make_float2(w, t.y);
  }
  const float denom = wred_sum(psum);
  const float invd = 1.0f / denom;
  const unsigned padded = (nc + 15u) & ~15u;
  if ((unsigned)lane < padded - nc) sc[nc + lane] = make_float2(0.f, __int_as_float(0));

  // ---- gather: 16 lanes x float4 per row, 16 entries per iter, wave-local ----
  const char* vpb = (const char*)(value + (size_t)h * (NSEQ * NB * VD)) + (lane & 15) * 16;
  floatx4 acc4 = {0.f, 0.f, 0.f, 0.f};
  for (unsigned t0 = 0; t0 < padded; t0 += 16) {
    unsigned j = t0 + (unsigned)(lane >> 4);
    float2 c0 = sc[j];        // 16-lane groups read same addr -> broadcast
    float2 c1 = sc[j + 4];
    float2 c2e = sc[j + 8];
    float2 c3 = sc[j + 12];
    floatx4 a0 = *reinterpret_cast<const floatx4*>(vpb + __float_as_int(c0.y));
    floatx4 a1 = *reinterpret_cast<const floatx4*>(vpb + __float_as_int(c1.y));
    floatx4 a2 = *reinterpret_cast<const floatx4*>(vpb + __float_as_int(c2e.y));
    floatx4 a3 = *reinterpret_cast<const floatx4*>(vpb + __float_as_int(c3.y));
    acc4.x = fmaf(c0.x, a0.x, acc4.x);
    acc4.y = fmaf(c0.x, a0.y, acc4.y);
    acc4.z = fmaf(c0.x, a0.z, acc4.z);
    acc4.w = fmaf(c0.x, a0.w, acc4.w);
    acc4.x = fmaf(c1.x, a1.x, acc4.x);
    acc4.y = fmaf(c1.x, a1.y, acc4.y);
    acc4.z = fmaf(c1.x, a1.z, acc4.z);
    acc4.w = fmaf(c1.x, a1.w, acc4.w);
    acc4.x = fmaf(c2e.x, a2.x, acc4.x);
    acc4.y = fmaf(c2e.x, a2.y, acc4.y);
    acc4.z = fmaf(c2e.x, a2.z, acc4.z);
    acc4.w = fmaf(c2e.x, a2.w, acc4.w);
    acc4.x = fmaf(c3.x, a3.x, acc4.x);
    acc4.y = fmaf(c3.x, a3.y, acc4.y);
    acc4.z = fmaf(c3.x, a3.z, acc4.z);
    acc4.w = fmaf(c3.x, a3.w, acc4.w);
  }
  // sum the 4 sixteen-lane groups (xor butterfly on d=16,32)
#pragma unroll
  for (int d = 16; d < 64; d <<= 1) {
    acc4.x += __shfl_xor(acc4.x, d, 64);
    acc4.y += __shfl_xor(acc4.y, d, 64);
    acc4.z += __shfl_xor(acc4.z, d, 64);
    acc4.w += __shfl_xor(acc4.w, d, 64);
  }

  if (lane < 16) {
    float o0 = gelu_tanh(acc4.x * invd);
    float o1 = gelu_tanh(acc4.y * invd);
    float o2 = gelu_tanh(acc4.z * invd);
    float o3 = gelu_tanh(acc4.w * invd);
    int col = lane * 4;
    int bb = col >> 5, kk = col & 31;
    float4 o4 = make_float4(o0, o1, o2, o3);
    *reinterpret_cast<float4*>(&out[((size_t)bb * NSEQ + q) * (NH * VD) + (size_t)h * VD + kk]) = o4;
  }
}

// ---------------- launch ----------------------------------------------------

extern "C" void kernel_launch(void* const* d_in, const int* in_sizes, int n_in,
                              void* d_out, int out_size, void* d_ws, size_t ws_size,
                              hipStream_t stream) {
  const float* m_dist = (const float*)d_in[0];
  const float* x = (const float*)d_in[1];
  const float* r = (const float*)d_in[2];
  const float* w = (const float*)d_in[3];
  float* out = (float*)d_out;

  float* value = (float*)d_ws;                          // NH*NSEQ*NB*VD floats = 8 MB
  float* scales = value + (size_t)NH * NSEQ * NB * VD;  // + 8 floats

  value_kernel<<<dim3(NSEQ / 8), dim3(256), 0, stream>>>(x, w, r, value, scales);
  attn_kernel<<<dim3(NH * NSEQ / 4), dim3(256), 0, stream>>>(m_dist, value, scales, out);
}

// Round 15
// 202.177 us; speedup vs baseline: 1.4730x; 1.3085x over previous
//
#include <hip/hip_runtime.h>
#include <hip/hip_bf16.h>
#include <math.h>

#define NH   8
#define NSEQ 4096
#define NB   2
#define HID  256
#define VD   32
#define RANK 409      // 0-indexed; pos = 0.1*(4096-1) = 409.5 -> lerp(s[409],s[410],0.5)
#define NBIN 128      // candidate-space histogram bins (per wave)
#define CAND 704      // per-wave candidate cap (mean 480, sd 20.6); multiple of 32
#define TG   0.1171875f  // raw-space threshold guess (scale>0 -> raw order == scaled order)

typedef float floatx4 __attribute__((ext_vector_type(4)));

__device__ __forceinline__ unsigned mbcnt64(unsigned long long m) {
  return __builtin_amdgcn_mbcnt_hi((unsigned)(m >> 32),
                                   __builtin_amdgcn_mbcnt_lo((unsigned)m, 0u));
}
__device__ __forceinline__ float wred_min(float x) {
#pragma unroll
  for (int d = 32; d; d >>= 1) x = fminf(x, __shfl_xor(x, d, 64));
  return x;
}
__device__ __forceinline__ float wred_max(float x) {
#pragma unroll
  for (int d = 32; d; d >>= 1) x = fmaxf(x, __shfl_xor(x, d, 64));
  return x;
}
__device__ __forceinline__ float wred_sum(float x) {
#pragma unroll
  for (int d = 32; d; d >>= 1) x += __shfl_xor(x, d, 64);
  return x;
}
__device__ __forceinline__ float gelu_tanh(float x) {
  float x3 = x * x * x;
  float inner = 0.7978845608028654f * (x + 0.044715f * x3);
  return 0.5f * x * (1.0f + tanhf(inner));
}
__device__ __forceinline__ float bflo(unsigned u) { return __uint_as_float(u << 16); }
__device__ __forceinline__ float bfhi(unsigned u) { return __uint_as_float(u & 0xFFFF0000u); }

// ---------------- kernel A: value_bf16[h][n][b*32+k] = x @ weight; + scales -

__global__ __launch_bounds__(256) void value_kernel(
    const float* __restrict__ x, const float* __restrict__ w,
    const float* __restrict__ r, __hip_bfloat16* __restrict__ value,
    float* __restrict__ scales) {
  const int tid = threadIdx.x;

  if (blockIdx.x == 0 && tid < NH) {
    double rv = (double)r[tid];
    const float c0 = (float)(0.25 * 3.141592653589793 * (1.0 - 1e-07));
    float s1 = (float)sin(rv);
    float t = c0 * (1.0f + s1);
    scales[tid] = (float)tan((double)t);
  }

  const int n0 = blockIdx.x * 8;
  __shared__ float sx[NB][8][HID];
#pragma unroll
  for (int i = 0; i < 16; i++) {
    int idx = i * 256 + tid;
    int b = idx >> 11;
    int rem = idx & 2047;
    int nn = rem >> 8;
    int j = rem & 255;
    sx[b][nn][j] = x[((size_t)b * NSEQ + n0 + nn) * HID + j];
  }
  __syncthreads();

  const int h = tid >> 5, k = tid & 31;
  float acc[NB][8];
#pragma unroll
  for (int b = 0; b < NB; b++)
#pragma unroll
    for (int nn = 0; nn < 8; nn++) acc[b][nn] = 0.f;

  const float* wp = w + (size_t)h * HID * VD + k;
  for (int j4 = 0; j4 < HID; j4 += 4) {
    float wv0 = wp[(size_t)(j4 + 0) * VD];
    float wv1 = wp[(size_t)(j4 + 1) * VD];
    float wv2 = wp[(size_t)(j4 + 2) * VD];
    float wv3 = wp[(size_t)(j4 + 3) * VD];
#pragma unroll
    for (int b = 0; b < NB; b++) {
#pragma unroll
      for (int nn = 0; nn < 8; nn++) {
        const float4 xv = *reinterpret_cast<const float4*>(&sx[b][nn][j4]);
        float a = acc[b][nn];
        a = fmaf(xv.x, wv0, a);
        a = fmaf(xv.y, wv1, a);
        a = fmaf(xv.z, wv2, a);
        a = fmaf(xv.w, wv3, a);
        acc[b][nn] = a;
      }
    }
  }
#pragma unroll
  for (int b = 0; b < NB; b++)
#pragma unroll
    for (int nn = 0; nn < 8; nn++)
      value[((size_t)h * NSEQ + n0 + nn) * (NB * VD) + b * VD + k] =
          __float2bfloat16(acc[b][nn]);
}

// ---------------- kernel B: ONE WAVE PER ROW, zero __syncthreads ------------
// Selection in RAW space; value table in bf16 (128 B rows, halves L2 bytes).
// Entry byte-offset = n*128 -> encode (G<<15)|(lane<<9)|(elem<<7).

#define PROCR(CV, G, T)                                                            \
  do {                                                                             \
    const int nb_ = ((G) << 15) | (lane << 9);                                     \
    { bool s = (CV).x <= (T); unsigned long long m = __ballot(s);                  \
      unsigned p = nc + mbcnt64(m);                                                \
      if (s && p < CAND) sc[p] = make_float2((CV).x, __int_as_float(nb_));         \
      nc += (unsigned)__popcll(m); }                                               \
    { bool s = (CV).y <= (T); unsigned long long m = __ballot(s);                  \
      unsigned p = nc + mbcnt64(m);                                                \
      if (s && p < CAND) sc[p] = make_float2((CV).y, __int_as_float(nb_ | 128));   \
      nc += (unsigned)__popcll(m); }                                               \
    { bool s = (CV).z <= (T); unsigned long long m = __ballot(s);                  \
      unsigned p = nc + mbcnt64(m);                                                \
      if (s && p < CAND) sc[p] = make_float2((CV).z, __int_as_float(nb_ | 256));   \
      nc += (unsigned)__popcll(m); }                                               \
    { bool s = (CV).w <= (T); unsigned long long m = __ballot(s);                  \
      unsigned p = nc + mbcnt64(m);                                                \
      if (s && p < CAND) sc[p] = make_float2((CV).w, __int_as_float(nb_ | 384));   \
      nc += (unsigned)__popcll(m); }                                               \
  } while (0)

#define PROCS(CV, G, TS)                                                                  \
  do {                                                                                    \
    const int nb_ = ((G) << 15) | (lane << 9);                                            \
    { float t_ = (CV).x * scale; bool s = t_ <= (TS); unsigned long long m = __ballot(s); \
      unsigned p = nc + mbcnt64(m);                                                       \
      if (s && p < CAND) sc[p] = make_float2(t_, __int_as_float(nb_));                    \
      nc += (unsigned)__popcll(m); }                                                      \
    { float t_ = (CV).y * scale; bool s = t_ <= (TS); unsigned long long m = __ballot(s); \
      unsigned p = nc + mbcnt64(m);                                                       \
      if (s && p < CAND) sc[p] = make_float2(t_, __int_as_float(nb_ | 128));              \
      nc += (unsigned)__popcll(m); }                                                      \
    { float t_ = (CV).z * scale; bool s = t_ <= (TS); unsigned long long m = __ballot(s); \
      unsigned p = nc + mbcnt64(m);                                                       \
      if (s && p < CAND) sc[p] = make_float2(t_, __int_as_float(nb_ | 256));              \
      nc += (unsigned)__popcll(m); }                                                      \
    { float t_ = (CV).w * scale; bool s = t_ <= (TS); unsigned long long m = __ballot(s); \
      unsigned p = nc + mbcnt64(m);                                                       \
      if (s && p < CAND) sc[p] = make_float2(t_, __int_as_float(nb_ | 384));              \
      nc += (unsigned)__popcll(m); }                                                      \
  } while (0)

#define CNT1(U)                                                        \
  do {                                                                 \
    bool s_ = (U) <= Tc;                                               \
    cN += (unsigned)__popcll(__ballot(s_));                            \
    if (s_) vb = fmaxf(vb, (U)); else vs = fminf(vs, (U));             \
  } while (0)

__global__ __launch_bounds__(256, 6) void attn_kernel(
    const float* __restrict__ m_dist, const __hip_bfloat16* __restrict__ value,
    const float* __restrict__ scales, float* __restrict__ out) {
  const int tid = threadIdx.x;
  const int lane = tid & 63;
  const int wv = tid >> 6;
  // 8192 blocks of 4 independent waves; bid&7 -> head == XCD (value L2-resident)
  const int bid = blockIdx.x;
  const int h = bid & 7;
  const int q = (bid >> 3) * 4 + wv;

  __shared__ float2 s_cand[4][CAND];   // 22528 B: per-wave (raw, byteoff)->(w, byteoff)
  __shared__ unsigned s_hist[4][NBIN]; // 2048 B
  __shared__ float s_small[4][48];     // 768 B
  __shared__ unsigned s_cnt[4];        // 16 B   (total 25360 B -> 6 blocks/CU)

  float2* sc = s_cand[wv];
  unsigned* sh = s_hist[wv];
  float* ssm = s_small[wv];
  unsigned* scn = &s_cnt[wv];

  const float scale = scales[h];
  const floatx4* row4 =
      reinterpret_cast<const floatx4*>(m_dist + ((size_t)(h * NSEQ + q)) * NSEQ) + lane;

  // ---- HOT stream: 4 loads in flight, threshold TG, RAW store ----
  unsigned nc = 0;
  {
    floatx4 c0 = __builtin_nontemporal_load(row4 + 0 * 64);
    floatx4 c1 = __builtin_nontemporal_load(row4 + 1 * 64);
    floatx4 n0 = __builtin_nontemporal_load(row4 + 2 * 64);
    floatx4 n1 = __builtin_nontemporal_load(row4 + 3 * 64);
    PROCR(c0, 0, TG); PROCR(c1, 1, TG);
    c0 = n0; c1 = n1;
    n0 = __builtin_nontemporal_load(row4 + 4 * 64);
    n1 = __builtin_nontemporal_load(row4 + 5 * 64);
    PROCR(c0, 2, TG); PROCR(c1, 3, TG);
    c0 = n0; c1 = n1;
    n0 = __builtin_nontemporal_load(row4 + 6 * 64);
    n1 = __builtin_nontemporal_load(row4 + 7 * 64);
    PROCR(c0, 4, TG); PROCR(c1, 5, TG);
    c0 = n0; c1 = n1;
    n0 = __builtin_nontemporal_load(row4 + 8 * 64);
    n1 = __builtin_nontemporal_load(row4 + 9 * 64);
    PROCR(c0, 6, TG); PROCR(c1, 7, TG);
    c0 = n0; c1 = n1;
    n0 = __builtin_nontemporal_load(row4 + 10 * 64);
    n1 = __builtin_nontemporal_load(row4 + 11 * 64);
    PROCR(c0, 8, TG); PROCR(c1, 9, TG);
    c0 = n0; c1 = n1;
    n0 = __builtin_nontemporal_load(row4 + 12 * 64);
    n1 = __builtin_nontemporal_load(row4 + 13 * 64);
    PROCR(c0, 10, TG); PROCR(c1, 11, TG);
    c0 = n0; c1 = n1;
    n0 = __builtin_nontemporal_load(row4 + 14 * 64);
    n1 = __builtin_nontemporal_load(row4 + 15 * 64);
    PROCR(c0, 12, TG); PROCR(c1, 13, TG);
    c0 = n0; c1 = n1;
    PROCR(c0, 14, TG); PROCR(c1, 15, TG);
  }

  float Tsel = TG;    // raw-space candidate range
  bool exact = false; // collapse path: sc holds SCALED values, ranks known
  float ex409 = 0.f, ex410 = 0.f;

  if (nc < (unsigned)(RANK + 2) || nc > (unsigned)CAND) {
    // ---- cold (wave-local, ~never on this data): count-only bisect ----
    float lo, hi;
    if (nc < (unsigned)(RANK + 2)) { lo = TG; hi = 1.0f; }
    else { lo = 0.f; hi = TG; }
    bool collapse = false, ok = false;
    for (int it = 0; it < 40; ++it) {
      float mid = 0.5f * (lo + hi);
      if (!(mid > lo && mid < hi)) { collapse = true; break; }
      unsigned cN = 0;
      float vb = -INFINITY, vs = INFINITY;
      const float Tc = mid;
#pragma unroll 2
      for (int ch = 0; ch < 16; ++ch) {
        floatx4 cv = __builtin_nontemporal_load(row4 + ch * 64);
        CNT1(cv.x); CNT1(cv.y); CNT1(cv.z); CNT1(cv.w);
      }
      if (cN >= (unsigned)(RANK + 2) && cN <= (unsigned)CAND) { Tsel = mid; ok = true; break; }
      if (cN < (unsigned)(RANK + 2)) lo = mid; else hi = mid;
    }
    if (collapse) {
      unsigned cN = 0;
      float vb = -INFINITY, vs = INFINITY;
      {
        const float Tc = lo;
#pragma unroll 2
        for (int ch = 0; ch < 16; ++ch) {
          floatx4 cv = __builtin_nontemporal_load(row4 + ch * 64);
          CNT1(cv.x); CNT1(cv.y); CNT1(cv.z); CNT1(cv.w);
        }
      }
      vb = wred_max(vb);
      vs = wred_min(vs);
      float s409r, s410r;
      if (cN >= (unsigned)(RANK + 2)) { s409r = vb; s410r = vb; }
      else if (cN == (unsigned)(RANK + 1)) { s409r = vb; s410r = vs; }
      else { s409r = vs; s410r = vs; }
      ex409 = s409r * scale;
      ex410 = s410r * scale;
      exact = true;
      float thrS = 0.5f * ex409 + 0.5f * ex410;
      nc = 0;
#pragma unroll 2
      for (int ch = 0; ch < 16; ++ch) {
        floatx4 cv = __builtin_nontemporal_load(row4 + ch * 64);
        PROCS(cv, ch, thrS);
      }
    } else if (ok) {
      nc = 0;
      const float Tf = Tsel;
#pragma unroll 2
      for (int ch = 0; ch < 16; ++ch) {
        floatx4 cv = __builtin_nontemporal_load(row4 + ch * 64);
        PROCR(cv, ch, Tf);
      }
    }
  }
  if (nc > (unsigned)CAND) nc = (unsigned)CAND;  // unreachable safety
  const float smul = exact ? 1.0f : scale;  // sc values raw (normal) / scaled (exact)

  // ---- per-wave 128-bin histogram over candidates + fused min (sc space) ----
  sh[lane] = 0u;
  sh[lane + 64] = 0u;
  const float binscale = exact ? 0.f : (float)NBIN / Tsel;
  float mn = INFINITY;
  for (unsigned e = lane; e < nc; e += 64) {
    float vv = sc[e].x;
    mn = fminf(mn, vv);
    int b = (int)(vv * binscale);
    b = b < 0 ? 0 : (b > NBIN - 1 ? NBIN - 1 : b);
    atomicAdd(&sh[b], 1u);
  }
  const float minT = wred_min(mn) * smul;  // scaled global min (monotone fl)

  float v409, v410;  // SCALED order statistics
  if (exact) {
    v409 = ex409;
    v410 = ex410;
  } else {
    // ---- locate rank bin: 2 bins/lane, wave exclusive scan ----
    unsigned c2 = sh[2 * lane] + sh[2 * lane + 1];
    unsigned incl = c2;
#pragma unroll
    for (int d = 1; d < 64; d <<= 1) {
      unsigned o = __shfl_up(incl, d, 64);
      if (lane >= d) incl += o;
    }
    unsigned b2 = incl - c2;
    unsigned tb_l = 0, bt_l = 0;
    bool win = (b2 <= (unsigned)RANK && (unsigned)RANK < b2 + c2);
    if (win) {
      unsigned h0 = sh[2 * lane];
      if ((unsigned)RANK < b2 + h0) { tb_l = 2u * lane; bt_l = b2; }
      else { tb_l = 2u * lane + 1u; bt_l = b2 + h0; }
    }
    unsigned long long wm = __ballot(win);
    int wl = (int)__ffsll(wm) - 1;
    if (wl < 0) wl = 0;  // unreachable guard
    unsigned tb = (unsigned)__shfl((int)tb_l, wl, 64);
    unsigned base_tb = (unsigned)__shfl((int)bt_l, wl, 64);

    // ---- in-bin collect + min-above-bin (raw) ----
    *scn = 0u;
    float mgt = INFINITY;
    for (unsigned e = lane; e < nc; e += 64) {
      float v = sc[e].x;
      int b = (int)(v * binscale);
      b = b < 0 ? 0 : (b > NBIN - 1 ? NBIN - 1 : b);
      if ((unsigned)b == tb) {
        unsigned p = atomicAdd(scn, 1u);
        if (p < 48u) ssm[p] = v;
      } else if ((unsigned)b > tb) {
        mgt = fminf(mgt, v);
      }
    }
    mgt = wred_min(mgt);
    unsigned cbin = *scn;

    // ---- exact raw ranks RANK / RANK+1 ----
    float r409, r410;
    if (cbin <= 48u) {
      float cand = (lane < (int)cbin) ? ssm[lane] : INFINITY;
      unsigned less = 0, eq = 0;
      for (unsigned k = 0; k < cbin; k++) {
        float g = ssm[k];
        less += (g < cand) ? 1u : 0u;
        eq += (g == cand) ? 1u : 0u;
      }
      unsigned gl = base_tb + less;
      bool w9 = (lane < (int)cbin) && gl <= (unsigned)RANK && (unsigned)RANK < gl + eq;
      bool w10 = (lane < (int)cbin) && gl <= (unsigned)(RANK + 1) && (unsigned)(RANK + 1) < gl + eq;
      r409 = wred_min(w9 ? cand : INFINITY);
      float t10 = wred_min(w10 ? cand : INFINITY);
      r410 = isinf(t10) ? mgt : t10;
    } else {
      // pathological clustering fallback: O(nc^2/64) exact (never taken here)
      float a9 = INFINITY, a10 = INFINITY;
      for (unsigned e = lane; e < nc; e += 64) {
        float v = sc[e].x;
        int b = (int)(v * binscale);
        b = b < 0 ? 0 : (b > NBIN - 1 ? NBIN - 1 : b);
        if ((unsigned)b == tb) {
          unsigned less = 0, eq = 0;
          for (unsigned k = 0; k < nc; k++) {
            float g = sc[k].x;
            less += (g < v) ? 1u : 0u;
            eq += (g == v) ? 1u : 0u;
          }
          if (less <= (unsigned)RANK && (unsigned)RANK < less + eq) a9 = v;
          if (less <= (unsigned)(RANK + 1) && (unsigned)(RANK + 1) < less + eq) a10 = v;
        }
      }
      r409 = wred_min(a9);
      float t10 = wred_min(a10);
      r410 = isinf(t10) ? mgt : t10;
    }
    if (isinf(r409)) r409 = mgt;  // unreachable guard
    v409 = r409 * scale;          // fl(sorted_raw[k]*scale) == sorted_scaled[k]
    v410 = r410 * scale;
  }
  const float thr = 0.5f * v409 + 0.5f * v410;  // jax lerp midpoint, frac=0.5

  // ---- weight pass (fixed strided order -> deterministic psum) ----
  float psum = 0.f;
  for (unsigned e = lane; e < nc; e += 64) {
    float2 t = sc[e];
    float ts = t.x * smul;  // scaled value
    float w = (ts <= thr) ? __expf(minT - ts) : 0.f;
    psum += w;
    sc[e] = make_float2(w, t.y);
  }
  const float denom = wred_sum(psum);
  const float invd = 1.0f / denom;
  const unsigned padded = (nc + 15u) & ~15u;
  if ((unsigned)lane < padded - nc) sc[nc + lane] = make_float2(0.f, __int_as_float(0));

  // ---- gather: bf16 rows (128 B); 8-lane groups x 16 B; 16 entries/iter ----
  const int g = lane >> 3;       // entry group 0..7
  const int c = lane & 7;        // col group: bf16 cols 8c..8c+7
  const char* vpb = (const char*)value + (size_t)h * (NSEQ * 128) + c * 16;
  float a0 = 0.f, a1 = 0.f, a2 = 0.f, a3 = 0.f, a4 = 0.f, a5 = 0.f, a6 = 0.f, a7 = 0.f;
  for (unsigned t0 = 0; t0 < padded; t0 += 16) {
    float2 e0 = sc[t0 + g];          // 8-lane groups read same addr -> broadcast
    float2 e1 = sc[t0 + 8 + g];
    const uint4 u0 = *reinterpret_cast<const uint4*>(vpb + __float_as_int(e0.y));
    const uint4 u1 = *reinterpret_cast<const uint4*>(vpb + __float_as_int(e1.y));
    float w0 = e0.x, w1 = e1.x;
    a0 = fmaf(w0, bflo(u0.x), a0);
    a1 = fmaf(w0, bfhi(u0.x), a1);
    a2 = fmaf(w0, bflo(u0.y), a2);
    a3 = fmaf(w0, bfhi(u0.y), a3);
    a4 = fmaf(w0, bflo(u0.z), a4);
    a5 = fmaf(w0, bfhi(u0.z), a5);
    a6 = fmaf(w0, bflo(u0.w), a6);
    a7 = fmaf(w0, bfhi(u0.w), a7);
    a0 = fmaf(w1, bflo(u1.x), a0);
    a1 = fmaf(w1, bfhi(u1.x), a1);
    a2 = fmaf(w1, bflo(u1.y), a2);
    a3 = fmaf(w1, bfhi(u1.y), a3);
    a4 = fmaf(w1, bflo(u1.z), a4);
    a5 = fmaf(w1, bfhi(u1.z), a5);
    a6 = fmaf(w1, bflo(u1.w), a6);
    a7 = fmaf(w1, bfhi(u1.w), a7);
  }
  // sum across the 8 entry-groups (lanes differing in bits 3..5)
#pragma unroll
  for (int d = 8; d < 64; d <<= 1) {
    a0 += __shfl_xor(a0, d, 64);
    a1 += __shfl_xor(a1, d, 64);
    a2 += __shfl_xor(a2, d, 64);
    a3 += __shfl_xor(a3, d, 64);
    a4 += __shfl_xor(a4, d, 64);
    a5 += __shfl_xor(a5, d, 64);
    a6 += __shfl_xor(a6, d, 64);
    a7 += __shfl_xor(a7, d, 64);
  }

  if (lane < 8) {
    // lane c covers cols 8c..8c+7; b = (8c)>>5, k = (8c)&31 (never crosses b)
    int col = c * 8;
    int bb = col >> 5, kk = col & 31;
    float* op = &out[((size_t)bb * NSEQ + q) * (NH * VD) + (size_t)h * VD + kk];
    float4 lo4 = make_float4(gelu_tanh(a0 * invd), gelu_tanh(a1 * invd),
                             gelu_tanh(a2 * invd), gelu_tanh(a3 * invd));
    float4 hi4 = make_float4(gelu_tanh(a4 * invd), gelu_tanh(a5 * invd),
                             gelu_tanh(a6 * invd), gelu_tanh(a7 * invd));
    *reinterpret_cast<float4*>(op) = lo4;
    *reinterpret_cast<float4*>(op + 4) = hi4;
  }
}

// ---------------- launch ----------------------------------------------------

extern "C" void kernel_launch(void* const* d_in, const int* in_sizes, int n_in,
                              void* d_out, int out_size, void* d_ws, size_t ws_size,
                              hipStream_t stream) {
  const float* m_dist = (const float*)d_in[0];
  const float* x = (const float*)d_in[1];
  const float* r = (const float*)d_in[2];
  const float* w = (const float*)d_in[3];
  float* out = (float*)d_out;

  __hip_bfloat16* value = (__hip_bfloat16*)d_ws;              // NH*NSEQ*64 bf16 = 4 MB
  float* scales = (float*)((char*)d_ws + (8u << 20));         // +8 MB offset, 8 floats

  value_kernel<<<dim3(NSEQ / 8), dim3(256), 0, stream>>>(x, w, r, value, scales);
  attn_kernel<<<dim3(NH * NSEQ / 4), dim3(256), 0, stream>>>(m_dist, value, scales, out);
}

// Round 17
// 192.727 us; speedup vs baseline: 1.5452x; 1.0490x over previous
//
#include <hip/hip_runtime.h>
#include <hip/hip_bf16.h>
#include <math.h>

#define NH   8
#define NSEQ 4096
#define NB   2
#define HID  256
#define VD   32
#define RANK 409      // 0-indexed; pos = 0.1*(4096-1) = 409.5 -> lerp(s[409],s[410],0.5)
#define NBIN 128      // candidate-space histogram bins (per wave)
#define CAND 704      // per-wave candidate cap (mean 480, sd 20.6); multiple of 32
#define TG   0.1171875f  // raw-space threshold guess (scale>0 -> raw order == scaled order)

typedef float floatx4 __attribute__((ext_vector_type(4)));

__device__ __forceinline__ unsigned mbcnt64(unsigned long long m) {
  return __builtin_amdgcn_mbcnt_hi((unsigned)(m >> 32),
                                   __builtin_amdgcn_mbcnt_lo((unsigned)m, 0u));
}
__device__ __forceinline__ float wred_min(float x) {
#pragma unroll
  for (int d = 32; d; d >>= 1) x = fminf(x, __shfl_xor(x, d, 64));
  return x;
}
__device__ __forceinline__ float wred_max(float x) {
#pragma unroll
  for (int d = 32; d; d >>= 1) x = fmaxf(x, __shfl_xor(x, d, 64));
  return x;
}
__device__ __forceinline__ float wred_sum(float x) {
#pragma unroll
  for (int d = 32; d; d >>= 1) x += __shfl_xor(x, d, 64);
  return x;
}
__device__ __forceinline__ float gelu_tanh(float x) {
  float x3 = x * x * x;
  float inner = 0.7978845608028654f * (x + 0.044715f * x3);
  return 0.5f * x * (1.0f + tanhf(inner));
}
__device__ __forceinline__ float bflo(unsigned u) { return __uint_as_float(u << 16); }
__device__ __forceinline__ float bfhi(unsigned u) { return __uint_as_float(u & 0xFFFF0000u); }

// ---------------- kernel A: value_bf16[h][n][b*32+k] = x @ weight; + scales -

__global__ __launch_bounds__(256) void value_kernel(
    const float* __restrict__ x, const float* __restrict__ w,
    const float* __restrict__ r, __hip_bfloat16* __restrict__ value,
    float* __restrict__ scales) {
  const int tid = threadIdx.x;

  if (blockIdx.x == 0 && tid < NH) {
    double rv = (double)r[tid];
    const float c0 = (float)(0.25 * 3.141592653589793 * (1.0 - 1e-07));
    float s1 = (float)sin(rv);
    float t = c0 * (1.0f + s1);
    scales[tid] = (float)tan((double)t);
  }

  const int n0 = blockIdx.x * 8;
  __shared__ float sx[NB][8][HID];
#pragma unroll
  for (int i = 0; i < 16; i++) {
    int idx = i * 256 + tid;
    int b = idx >> 11;
    int rem = idx & 2047;
    int nn = rem >> 8;
    int j = rem & 255;
    sx[b][nn][j] = x[((size_t)b * NSEQ + n0 + nn) * HID + j];
  }
  __syncthreads();

  const int h = tid >> 5, k = tid & 31;
  float acc[NB][8];
#pragma unroll
  for (int b = 0; b < NB; b++)
#pragma unroll
    for (int nn = 0; nn < 8; nn++) acc[b][nn] = 0.f;

  const float* wp = w + (size_t)h * HID * VD + k;
  for (int j4 = 0; j4 < HID; j4 += 4) {
    float wv0 = wp[(size_t)(j4 + 0) * VD];
    float wv1 = wp[(size_t)(j4 + 1) * VD];
    float wv2 = wp[(size_t)(j4 + 2) * VD];
    float wv3 = wp[(size_t)(j4 + 3) * VD];
#pragma unroll
    for (int b = 0; b < NB; b++) {
#pragma unroll
      for (int nn = 0; nn < 8; nn++) {
        const float4 xv = *reinterpret_cast<const float4*>(&sx[b][nn][j4]);
        float a = acc[b][nn];
        a = fmaf(xv.x, wv0, a);
        a = fmaf(xv.y, wv1, a);
        a = fmaf(xv.z, wv2, a);
        a = fmaf(xv.w, wv3, a);
        acc[b][nn] = a;
      }
    }
  }
#pragma unroll
  for (int b = 0; b < NB; b++)
#pragma unroll
    for (int nn = 0; nn < 8; nn++)
      value[((size_t)h * NSEQ + n0 + nn) * (NB * VD) + b * VD + k] =
          __float2bfloat16(acc[b][nn]);
}

// ---------------- kernel B: ONE WAVE PER ROW, zero __syncthreads ------------
// Selection in RAW space; value table bf16 (128 B rows). Entry byte-offset =
// n*128 -> encode (G<<15)|(lane<<9)|(elem<<7).

#define PROCR(CV, G, T)                                                            \
  do {                                                                             \
    const int nb_ = ((G) << 15) | (lane << 9);                                     \
    { bool s = (CV).x <= (T); unsigned long long m = __ballot(s);                  \
      unsigned p = nc + mbcnt64(m);                                                \
      if (s && p < CAND) sc[p] = make_float2((CV).x, __int_as_float(nb_));         \
      nc += (unsigned)__popcll(m); }                                               \
    { bool s = (CV).y <= (T); unsigned long long m = __ballot(s);                  \
      unsigned p = nc + mbcnt64(m);                                                \
      if (s && p < CAND) sc[p] = make_float2((CV).y, __int_as_float(nb_ | 128));   \
      nc += (unsigned)__popcll(m); }                                               \
    { bool s = (CV).z <= (T); unsigned long long m = __ballot(s);                  \
      unsigned p = nc + mbcnt64(m);                                                \
      if (s && p < CAND) sc[p] = make_float2((CV).z, __int_as_float(nb_ | 256));   \
      nc += (unsigned)__popcll(m); }                                               \
    { bool s = (CV).w <= (T); unsigned long long m = __ballot(s);                  \
      unsigned p = nc + mbcnt64(m);                                                \
      if (s && p < CAND) sc[p] = make_float2((CV).w, __int_as_float(nb_ | 384));   \
      nc += (unsigned)__popcll(m); }                                               \
  } while (0)

#define PROCS(CV, G, TS)                                                                  \
  do {                                                                                    \
    const int nb_ = ((G) << 15) | (lane << 9);                                            \
    { float t_ = (CV).x * scale; bool s = t_ <= (TS); unsigned long long m = __ballot(s); \
      unsigned p = nc + mbcnt64(m);                                                       \
      if (s && p < CAND) sc[p] = make_float2(t_, __int_as_float(nb_));                    \
      nc += (unsigned)__popcll(m); }                                                      \
    { float t_ = (CV).y * scale; bool s = t_ <= (TS); unsigned long long m = __ballot(s); \
      unsigned p = nc + mbcnt64(m);                                                       \
      if (s && p < CAND) sc[p] = make_float2(t_, __int_as_float(nb_ | 128));              \
      nc += (unsigned)__popcll(m); }                                                      \
    { float t_ = (CV).z * scale; bool s = t_ <= (TS); unsigned long long m = __ballot(s); \
      unsigned p = nc + mbcnt64(m);                                                       \
      if (s && p < CAND) sc[p] = make_float2(t_, __int_as_float(nb_ | 256));              \
      nc += (unsigned)__popcll(m); }                                                      \
    { float t_ = (CV).w * scale; bool s = t_ <= (TS); unsigned long long m = __ballot(s); \
      unsigned p = nc + mbcnt64(m);                                                       \
      if (s && p < CAND) sc[p] = make_float2(t_, __int_as_float(nb_ | 384));              \
      nc += (unsigned)__popcll(m); }                                                      \
  } while (0)

#define CNT1(U)                                                        \
  do {                                                                 \
    bool s_ = (U) <= Tc;                                               \
    cN += (unsigned)__popcll(__ballot(s_));                            \
    if (s_) vb = fmaxf(vb, (U)); else vs = fminf(vs, (U));             \
  } while (0)

__global__ __launch_bounds__(256, 5) void attn_kernel(
    const float* __restrict__ m_dist, const __hip_bfloat16* __restrict__ value,
    const float* __restrict__ scales, float* __restrict__ out) {
  const int tid = threadIdx.x;
  const int lane = tid & 63;
  const int wv = tid >> 6;
  // 8192 blocks of 4 independent waves; bid&7 -> head == XCD (value L2-resident)
  const int bid = blockIdx.x;
  const int h = bid & 7;
  const int q = (bid >> 3) * 4 + wv;

  __shared__ float2 s_cand[4][CAND];   // 22528 B: per-wave (raw, byteoff)->(w, byteoff)
  __shared__ unsigned s_hist[4][NBIN]; // 2048 B
  __shared__ float s_small[4][48];     // 768 B
  __shared__ unsigned s_cnt[4];        // 16 B

  float2* sc = s_cand[wv];
  unsigned* sh = s_hist[wv];
  float* ssm = s_small[wv];
  unsigned* scn = &s_cnt[wv];

  const float scale = scales[h];
  const floatx4* row4 =
      reinterpret_cast<const floatx4*>(m_dist + ((size_t)(h * NSEQ + q)) * NSEQ) + lane;

  // ---- HOT stream: 4 loads in flight, threshold TG, RAW store ----
  unsigned nc = 0;
  {
    floatx4 c0 = __builtin_nontemporal_load(row4 + 0 * 64);
    floatx4 c1 = __builtin_nontemporal_load(row4 + 1 * 64);
    floatx4 n0 = __builtin_nontemporal_load(row4 + 2 * 64);
    floatx4 n1 = __builtin_nontemporal_load(row4 + 3 * 64);
    PROCR(c0, 0, TG); PROCR(c1, 1, TG);
    c0 = n0; c1 = n1;
    n0 = __builtin_nontemporal_load(row4 + 4 * 64);
    n1 = __builtin_nontemporal_load(row4 + 5 * 64);
    PROCR(c0, 2, TG); PROCR(c1, 3, TG);
    c0 = n0; c1 = n1;
    n0 = __builtin_nontemporal_load(row4 + 6 * 64);
    n1 = __builtin_nontemporal_load(row4 + 7 * 64);
    PROCR(c0, 4, TG); PROCR(c1, 5, TG);
    c0 = n0; c1 = n1;
    n0 = __builtin_nontemporal_load(row4 + 8 * 64);
    n1 = __builtin_nontemporal_load(row4 + 9 * 64);
    PROCR(c0, 6, TG); PROCR(c1, 7, TG);
    c0 = n0; c1 = n1;
    n0 = __builtin_nontemporal_load(row4 + 10 * 64);
    n1 = __builtin_nontemporal_load(row4 + 11 * 64);
    PROCR(c0, 8, TG); PROCR(c1, 9, TG);
    c0 = n0; c1 = n1;
    n0 = __builtin_nontemporal_load(row4 + 12 * 64);
    n1 = __builtin_nontemporal_load(row4 + 13 * 64);
    PROCR(c0, 10, TG); PROCR(c1, 11, TG);
    c0 = n0; c1 = n1;
    n0 = __builtin_nontemporal_load(row4 + 14 * 64);
    n1 = __builtin_nontemporal_load(row4 + 15 * 64);
    PROCR(c0, 12, TG); PROCR(c1, 13, TG);
    c0 = n0; c1 = n1;
    PROCR(c0, 14, TG); PROCR(c1, 15, TG);
  }

  float Tsel = TG;    // raw-space candidate range
  bool exact = false; // collapse path: sc holds SCALED values, ranks known
  float ex409 = 0.f, ex410 = 0.f;

  if (nc < (unsigned)(RANK + 2) || nc > (unsigned)CAND) {
    // ---- cold (wave-local, ~never on this data): count-only bisect ----
    float lo, hi;
    if (nc < (unsigned)(RANK + 2)) { lo = TG; hi = 1.0f; }
    else { lo = 0.f; hi = TG; }
    bool collapse = false, ok = false;
    for (int it = 0; it < 40; ++it) {
      float mid = 0.5f * (lo + hi);
      if (!(mid > lo && mid < hi)) { collapse = true; break; }
      unsigned cN = 0;
      float vb = -INFINITY, vs = INFINITY;
      const float Tc = mid;
#pragma unroll 2
      for (int ch = 0; ch < 16; ++ch) {
        floatx4 cv = __builtin_nontemporal_load(row4 + ch * 64);
        CNT1(cv.x); CNT1(cv.y); CNT1(cv.z); CNT1(cv.w);
      }
      if (cN >= (unsigned)(RANK + 2) && cN <= (unsigned)CAND) { Tsel = mid; ok = true; break; }
      if (cN < (unsigned)(RANK + 2)) lo = mid; else hi = mid;
    }
    if (collapse) {
      unsigned cN = 0;
      float vb = -INFINITY, vs = INFINITY;
      {
        const float Tc = lo;
#pragma unroll 2
        for (int ch = 0; ch < 16; ++ch) {
          floatx4 cv = __builtin_nontemporal_load(row4 + ch * 64);
          CNT1(cv.x); CNT1(cv.y); CNT1(cv.z); CNT1(cv.w);
        }
      }
      vb = wred_max(vb);
      vs = wred_min(vs);
      float s409r, s410r;
      if (cN >= (unsigned)(RANK + 2)) { s409r = vb; s410r = vb; }
      else if (cN == (unsigned)(RANK + 1)) { s409r = vb; s410r = vs; }
      else { s409r = vs; s410r = vs; }
      ex409 = s409r * scale;
      ex410 = s410r * scale;
      exact = true;
      float thrS = 0.5f * ex409 + 0.5f * ex410;
      nc = 0;
#pragma unroll 2
      for (int ch = 0; ch < 16; ++ch) {
        floatx4 cv = __builtin_nontemporal_load(row4 + ch * 64);
        PROCS(cv, ch, thrS);
      }
    } else if (ok) {
      nc = 0;
      const float Tf = Tsel;
#pragma unroll 2
      for (int ch = 0; ch < 16; ++ch) {
        floatx4 cv = __builtin_nontemporal_load(row4 + ch * 64);
        PROCR(cv, ch, Tf);
      }
    }
  }
  if (nc > (unsigned)CAND) nc = (unsigned)CAND;  // unreachable safety
  const float smul = exact ? 1.0f : scale;  // sc values raw (normal) / scaled (exact)

  // ---- per-wave 128-bin histogram over candidates + fused min (sc space) ----
  sh[lane] = 0u;
  sh[lane + 64] = 0u;
  const float binscale = exact ? 0.f : (float)NBIN / Tsel;
  float mn = INFINITY;
  for (unsigned e = lane; e < nc; e += 64) {
    float vv = sc[e].x;
    mn = fminf(mn, vv);
    int b = (int)(vv * binscale);
    b = b < 0 ? 0 : (b > NBIN - 1 ? NBIN - 1 : b);
    atomicAdd(&sh[b], 1u);
  }
  const float minT = wred_min(mn) * smul;  // scaled global min (monotone fl)

  float v409, v410;  // SCALED order statistics
  if (exact) {
    v409 = ex409;
    v410 = ex410;
  } else {
    // ---- locate rank bin: 2 bins/lane, wave exclusive scan ----
    unsigned c2 = sh[2 * lane] + sh[2 * lane + 1];
    unsigned incl = c2;
#pragma unroll
    for (int d = 1; d < 64; d <<= 1) {
      unsigned o = __shfl_up(incl, d, 64);
      if (lane >= d) incl += o;
    }
    unsigned b2 = incl - c2;
    unsigned tb_l = 0, bt_l = 0;
    bool win = (b2 <= (unsigned)RANK && (unsigned)RANK < b2 + c2);
    if (win) {
      unsigned h0 = sh[2 * lane];
      if ((unsigned)RANK < b2 + h0) { tb_l = 2u * lane; bt_l = b2; }
      else { tb_l = 2u * lane + 1u; bt_l = b2 + h0; }
    }
    unsigned long long wm = __ballot(win);
    int wl = (int)__ffsll(wm) - 1;
    if (wl < 0) wl = 0;  // unreachable guard
    unsigned tb = (unsigned)__shfl((int)tb_l, wl, 64);
    unsigned base_tb = (unsigned)__shfl((int)bt_l, wl, 64);

    // ---- in-bin collect + min-above-bin (raw) ----
    *scn = 0u;
    float mgt = INFINITY;
    for (unsigned e = lane; e < nc; e += 64) {
      float v = sc[e].x;
      int b = (int)(v * binscale);
      b = b < 0 ? 0 : (b > NBIN - 1 ? NBIN - 1 : b);
      if ((unsigned)b == tb) {
        unsigned p = atomicAdd(scn, 1u);
        if (p < 48u) ssm[p] = v;
      } else if ((unsigned)b > tb) {
        mgt = fminf(mgt, v);
      }
    }
    mgt = wred_min(mgt);
    unsigned cbin = *scn;

    // ---- exact raw ranks RANK / RANK+1 ----
    float r409, r410;
    if (cbin <= 48u) {
      float cand = (lane < (int)cbin) ? ssm[lane] : INFINITY;
      unsigned less = 0, eq = 0;
      for (unsigned k = 0; k < cbin; k++) {
        float g = ssm[k];
        less += (g < cand) ? 1u : 0u;
        eq += (g == cand) ? 1u : 0u;
      }
      unsigned gl = base_tb + less;
      bool w9 = (lane < (int)cbin) && gl <= (unsigned)RANK && (unsigned)RANK < gl + eq;
      bool w10 = (lane < (int)cbin) && gl <= (unsigned)(RANK + 1) && (unsigned)(RANK + 1) < gl + eq;
      r409 = wred_min(w9 ? cand : INFINITY);
      float t10 = wred_min(w10 ? cand : INFINITY);
      r410 = isinf(t10) ? mgt : t10;
    } else {
      // pathological clustering fallback: O(nc^2/64) exact (never taken here)
      float a9 = INFINITY, a10 = INFINITY;
      for (unsigned e = lane; e < nc; e += 64) {
        float v = sc[e].x;
        int b = (int)(v * binscale);
        b = b < 0 ? 0 : (b > NBIN - 1 ? NBIN - 1 : b);
        if ((unsigned)b == tb) {
          unsigned less = 0, eq = 0;
          for (unsigned k = 0; k < nc; k++) {
            float g = sc[k].x;
            less += (g < v) ? 1u : 0u;
            eq += (g == v) ? 1u : 0u;
          }
          if (less <= (unsigned)RANK && (unsigned)RANK < less + eq) a9 = v;
          if (less <= (unsigned)(RANK + 1) && (unsigned)(RANK + 1) < less + eq) a10 = v;
        }
      }
      r409 = wred_min(a9);
      float t10 = wred_min(a10);
      r410 = isinf(t10) ? mgt : t10;
    }
    if (isinf(r409)) r409 = mgt;  // unreachable guard
    v409 = r409 * scale;          // fl(sorted_raw[k]*scale) == sorted_scaled[k]
    v410 = r410 * scale;
  }
  const float thr = 0.5f * v409 + 0.5f * v410;  // jax lerp midpoint, frac=0.5

  // ---- weight pass + in-place compaction (fixed order -> deterministic) ----
  // In-place safe: within an iteration all lane-reads precede the write instr
  // (lockstep wave); cross-iter, write positions < 64*(i+1) <= next read base.
  float psum = 0.f;
  unsigned mq = 0;
  for (unsigned e = lane; e < nc; e += 64) {
    float2 t = sc[e];
    float ts = t.x * smul;  // scaled value
    bool sel = (ts <= thr);
    float w = sel ? __expf(minT - ts) : 0.f;
    psum += w;
    unsigned long long m = __ballot(sel);
    unsigned p = mq + mbcnt64(m);
    if (sel) sc[p] = make_float2(w, t.y);
    mq += (unsigned)__popcll(m);
  }
  // mq is loop-carried and the trip count is divergent (nc % 64 != 0): lanes
  // that skip the final partial iteration miss its popcll. Lane 0 always runs
  // the maximal iteration count -> holds the true total. Broadcast it.
  mq = (unsigned)__shfl((int)mq, 0, 64);
  const float denom = wred_sum(psum);
  const float invd = 1.0f / denom;
  const unsigned padded = (mq + 31u) & ~31u;
  for (unsigned e = mq + lane; e < padded; e += 64) sc[e] = make_float2(0.f, __int_as_float(0));

  // ---- gather: bf16 rows (128 B); 8-lane groups x 16 B; 32 entries/iter ----
  const int g = lane >> 3;       // entry group 0..7
  const int c = lane & 7;        // col group: bf16 cols 8c..8c+7
  const char* vpb = (const char*)value + (size_t)h * (NSEQ * 128) + c * 16;
  float a0 = 0.f, a1 = 0.f, a2 = 0.f, a3 = 0.f, a4 = 0.f, a5 = 0.f, a6 = 0.f, a7 = 0.f;
  for (unsigned t0 = 0; t0 < padded; t0 += 32) {
    float2 e0 = sc[t0 + g];          // 8-lane groups read same addr -> broadcast
    float2 e1 = sc[t0 + 8 + g];
    float2 e2 = sc[t0 + 16 + g];
    float2 e3 = sc[t0 + 24 + g];
    const uint4 u0 = *reinterpret_cast<const uint4*>(vpb + __float_as_int(e0.y));
    const uint4 u1 = *reinterpret_cast<const uint4*>(vpb + __float_as_int(e1.y));
    const uint4 u2 = *reinterpret_cast<const uint4*>(vpb + __float_as_int(e2.y));
    const uint4 u3 = *reinterpret_cast<const uint4*>(vpb + __float_as_int(e3.y));
    float w0 = e0.x, w1 = e1.x, w2 = e2.x, w3 = e3.x;
    a0 = fmaf(w0, bflo(u0.x), a0);
    a1 = fmaf(w0, bfhi(u0.x), a1);
    a2 = fmaf(w0, bflo(u0.y), a2);
    a3 = fmaf(w0, bfhi(u0.y), a3);
    a4 = fmaf(w0, bflo(u0.z), a4);
    a5 = fmaf(w0, bfhi(u0.z), a5);
    a6 = fmaf(w0, bflo(u0.w), a6);
    a7 = fmaf(w0, bfhi(u0.w), a7);
    a0 = fmaf(w1, bflo(u1.x), a0);
    a1 = fmaf(w1, bfhi(u1.x), a1);
    a2 = fmaf(w1, bflo(u1.y), a2);
    a3 = fmaf(w1, bfhi(u1.y), a3);
    a4 = fmaf(w1, bflo(u1.z), a4);
    a5 = fmaf(w1, bfhi(u1.z), a5);
    a6 = fmaf(w1, bflo(u1.w), a6);
    a7 = fmaf(w1, bfhi(u1.w), a7);
    a0 = fmaf(w2, bflo(u2.x), a0);
    a1 = fmaf(w2, bfhi(u2.x), a1);
    a2 = fmaf(w2, bflo(u2.y), a2);
    a3 = fmaf(w2, bfhi(u2.y), a3);
    a4 = fmaf(w2, bflo(u2.z), a4);
    a5 = fmaf(w2, bfhi(u2.z), a5);
    a6 = fmaf(w2, bflo(u2.w), a6);
    a7 = fmaf(w2, bfhi(u2.w), a7);
    a0 = fmaf(w3, bflo(u3.x), a0);
    a1 = fmaf(w3, bfhi(u3.x), a1);
    a2 = fmaf(w3, bflo(u3.y), a2);
    a3 = fmaf(w3, bfhi(u3.y), a3);
    a4 = fmaf(w3, bflo(u3.z), a4);
    a5 = fmaf(w3, bfhi(u3.z), a5);
    a6 = fmaf(w3, bflo(u3.w), a6);
    a7 = fmaf(w3, bfhi(u3.w), a7);
  }
  // sum across the 8 entry-groups (lanes differing in bits 3..5)
#pragma unroll
  for (int d = 8; d < 64; d <<= 1) {
    a0 += __shfl_xor(a0, d, 64);
    a1 += __shfl_xor(a1, d, 64);
    a2 += __shfl_xor(a2, d, 64);
    a3 += __shfl_xor(a3, d, 64);
    a4 += __shfl_xor(a4, d, 64);
    a5 += __shfl_xor(a5, d, 64);
    a6 += __shfl_xor(a6, d, 64);
    a7 += __shfl_xor(a7, d, 64);
  }

  if (lane < 8) {
    // lane c covers cols 8c..8c+7; b = (8c)>>5, k = (8c)&31 (never crosses b)
    int col = c * 8;
    int bb = col >> 5, kk = col & 31;
    float* op = &out[((size_t)bb * NSEQ + q) * (NH * VD) + (size_t)h * VD + kk];
    float4 lo4 = make_float4(gelu_tanh(a0 * invd), gelu_tanh(a1 * invd),
                             gelu_tanh(a2 * invd), gelu_tanh(a3 * invd));
    float4 hi4 = make_float4(gelu_tanh(a4 * invd), gelu_tanh(a5 * invd),
                             gelu_tanh(a6 * invd), gelu_tanh(a7 * invd));
    *reinterpret_cast<float4*>(op) = lo4;
    *reinterpret_cast<float4*>(op + 4) = hi4;
  }
}

// ---------------- launch ----------------------------------------------------

extern "C" void kernel_launch(void* const* d_in, const int* in_sizes, int n_in,
                              void* d_out, int out_size, void* d_ws, size_t ws_size,
                              hipStream_t stream) {
  const float* m_dist = (const float*)d_in[0];
  const float* x = (const float*)d_in[1];
  const float* r = (const float*)d_in[2];
  const float* w = (const float*)d_in[3];
  float* out = (float*)d_out;

  __hip_bfloat16* value = (__hip_bfloat16*)d_ws;              // NH*NSEQ*64 bf16 = 4 MB
  float* scales = (float*)((char*)d_ws + (8u << 20));         // +8 MB offset, 8 floats

  value_kernel<<<dim3(NSEQ / 8), dim3(256), 0, stream>>>(x, w, r, value, scales);
  attn_kernel<<<dim3(NH * NSEQ / 4), dim3(256), 0, stream>>>(m_dist, value, scales, out);
}